// Round 5
// baseline (679.616 us; speedup 1.0000x reference)
//
#include <hip/hip_runtime.h>
#include <hip/hip_bf16.h>

#define MM 127
#define CHUNK_U16 4096        // per (matrix, k-chunk): 128 rows x 32 k = 8 KB
#define MAT_U16   16384       // 4 chunks per matrix
#define ARR_U16   1048576     // 64 matrices = 2 MB per array (Xhi/Xlo/Yhi/Ylo)
#define SLOT_U16  16384       // Mp slot [128][128] bf16 = 32 KB
#define NSLOT 2
#define QITER 20              // PDE iters per gap: 254 -> 13 gaps, slot window is 15

typedef __attribute__((ext_vector_type(8))) short short8;
typedef __attribute__((ext_vector_type(4))) float floatx4;

__device__ __forceinline__ unsigned short f2bf_rne(float x) {
  unsigned int u = __float_as_uint(x);
  u += 0x7FFFu + ((u >> 16) & 1u);
  return (unsigned short)(u >> 16);
}

__device__ __forceinline__ void decode_pair(int p, int& a, int& b,
                                            int& srcA, int& srcB, float& w) {
  if (p < 4160) {
    srcA = 0;
    if (p >= 2080) { p -= 2080; srcA = 1; }
    srcB = srcA;
    int ia = (int)((sqrtf(8.0f * (float)p + 1.0f) - 1.0f) * 0.5f);
    while ((ia + 1) * (ia + 2) / 2 <= p) ia++;
    while (ia * (ia + 1) / 2 > p) ia--;
    b = p - ia * (ia + 1) / 2;
    a = ia;
    w = (a == b ? 1.0f : 2.0f) / 4096.0f;
  } else {
    p -= 4160;
    a = p >> 6; b = p & 63;
    srcA = 0; srcB = 1;
    w = -2.0f / 4096.0f;
  }
}

// ---- prep: increments -> hi/lo bf16 split, frag-image layout (no swizzle) ----
// chunk c of matrix m: u16 idx = r*32 + k'  (k' = k - 32c), rows 0..127
__global__ __launch_bounds__(256) void prep_kernel(
    const float* __restrict__ X, const float* __restrict__ Y,
    unsigned short* __restrict__ base, float* __restrict__ acc)
{
  if (blockIdx.x == 0 && threadIdx.x == 0) acc[0] = 0.f;
  const int bid = blockIdx.x;          // 0..511
  const int c = bid & 3;
  const int m = (bid >> 2) & 63;
  const int isY = bid >> 8;
  const float* src = (isY ? Y : X) + m * 128 * 128;
  unsigned short* dhi = base + isY * 2 * ARR_U16 + m * MAT_U16 + c * CHUNK_U16;
  unsigned short* dlo = dhi + ARR_U16;

  for (int s = threadIdx.x; s < 512; s += 256) {
    const int r = s >> 2;
    const int g = s & 3;
    uint4 hv = make_uint4(0, 0, 0, 0), lv = make_uint4(0, 0, 0, 0);
    if (r < MM) {
      const float* p = src + r * 128 + c * 32 + g * 8;
      float4 u0 = *reinterpret_cast<const float4*>(p);
      float4 u1 = *reinterpret_cast<const float4*>(p + 4);
      float4 v0 = *reinterpret_cast<const float4*>(p + 128);
      float4 v1 = *reinterpret_cast<const float4*>(p + 132);
      float d[8] = {v0.x - u0.x, v0.y - u0.y, v0.z - u0.z, v0.w - u0.w,
                    v1.x - u1.x, v1.y - u1.y, v1.z - u1.z, v1.w - u1.w};
      unsigned int hw[4], lw[4];
#pragma unroll
      for (int e = 0; e < 4; ++e) {
        unsigned int a0 = __float_as_uint(d[2 * e]);
        unsigned int a1 = __float_as_uint(d[2 * e + 1]);
        hw[e] = (a0 >> 16) | (a1 & 0xFFFF0000u);          // truncated-hi pair
        float r0 = d[2 * e]     - __uint_as_float(a0 & 0xFFFF0000u);
        float r1 = d[2 * e + 1] - __uint_as_float(a1 & 0xFFFF0000u);
        float2 rr; rr.x = r0; rr.y = r1;
        __hip_bfloat162 lp = __float22bfloat162_rn(rr);
        unsigned int lu; __builtin_memcpy(&lu, &lp, 4);
        lw[e] = lu;
      }
      hv = make_uint4(hw[0], hw[1], hw[2], hw[3]);
      lv = make_uint4(lw[0], lw[1], lw[2], lw[3]);
    }
    *reinterpret_cast<uint4*>(dhi + s * 8) = hv;
    *reinterpret_cast<uint4*>(dlo + s * 8) = lv;
  }
}

// ---- fused producer/consumer: waves 0-3 GEMM, waves 4-7 PDE ----
__global__ __launch_bounds__(512, 4) void sig_fused_kernel(
    const unsigned short* __restrict__ base, float* __restrict__ acc)
{
  __shared__ unsigned short slots[NSLOT * SLOT_U16];   // 65,536 B exactly
  const int tid = threadIdx.x;
  const int wid = tid >> 6, lane = tid & 63;
  const int B = blockIdx.x;
  const int P_blk = (B < 64) ? 17 : 16;   // 512*16 + 64 = 8256 pairs total

  // producer state (waves 0-3)
  const int row0 = (wid >> 1) * 64, col0 = (wid & 1) * 64;
  const int lrow = lane & 15, quad = lane >> 4;
  floatx4 acc4[4][4];
  const unsigned short *pAh = base, *pAl = base, *pBh = base, *pBl = base;

  // consumer state (waves 4-7); cw = wid-4 handles local pairs cw, cw+4, ...
  int cons_p = wid - 4;
  int cons_active = 0;
  int d1 = 1;
  float cur1 = 1.f, cur2 = 1.f, np1 = 1.f, np2 = 1.f, cw_w = 0.f;
  const unsigned short* cslot = slots;

  for (int per = 0; per < P_blk + 2; ++per) {
    for (int g = 0; g < 8; ++g) {
      __syncthreads();
      if (wid < 4) {
        // ------------- producer -------------
        if (per < P_blk) {
          if (g == 0) {
            int a, b, sA, sB; float w_;
            decode_pair(B + per * 512, a, b, sA, sB, w_);
            pAh = base + sA * 2 * ARR_U16 + a * MAT_U16;
            pAl = pAh + ARR_U16;
            pBh = base + sB * 2 * ARR_U16 + b * MAT_U16;
            pBl = pBh + ARR_U16;
#pragma unroll
            for (int tr = 0; tr < 4; ++tr)
#pragma unroll
              for (int tc = 0; tc < 4; ++tc)
                acc4[tr][tc] = (floatx4){0.f, 0.f, 0.f, 0.f};
          }
          if (g < 4) {
            // k-chunk g: direct global->VGPR fragment loads (L2/L3-resident)
            const unsigned short* gbh = pBh + g * CHUNK_U16;
            const unsigned short* gbl = pBl + g * CHUNK_U16;
            short8 bh[4], bl[4];
#pragma unroll
            for (int tc = 0; tc < 4; ++tc) {
              int off = (col0 + tc * 16 + lrow) * 32 + quad * 8;
              bh[tc] = *reinterpret_cast<const short8*>(gbh + off);
              bl[tc] = *reinterpret_cast<const short8*>(gbl + off);
            }
            const unsigned short* gah = pAh + g * CHUNK_U16;
            const unsigned short* gal = pAl + g * CHUNK_U16;
#pragma unroll
            for (int tr = 0; tr < 4; ++tr) {
              int off = (row0 + tr * 16 + lrow) * 32 + quad * 8;
              short8 ah = *reinterpret_cast<const short8*>(gah + off);
              short8 al = *reinterpret_cast<const short8*>(gal + off);
#pragma unroll
              for (int tc = 0; tc < 4; ++tc) {
                acc4[tr][tc] = __builtin_amdgcn_mfma_f32_16x16x32_bf16(ah, bh[tc], acc4[tr][tc], 0, 0, 0);
                acc4[tr][tc] = __builtin_amdgcn_mfma_f32_16x16x32_bf16(ah, bl[tc], acc4[tr][tc], 0, 0, 0);
                acc4[tr][tc] = __builtin_amdgcn_mfma_f32_16x16x32_bf16(al, bh[tc], acc4[tr][tc], 0, 0, 0);
              }
            }
          } else if (g == 4) {
            // epilogue: bordered Mp (bf16) into slot per%2
            unsigned short* slot = slots + (per % NSLOT) * SLOT_U16;
            if (tid < 128) { slot[tid] = 0; slot[tid * 128] = 0; }
#pragma unroll
            for (int tr = 0; tr < 4; ++tr) {
#pragma unroll
              for (int tc = 0; tc < 4; ++tc) {
                int j = col0 + tc * 16 + lrow;
#pragma unroll
                for (int e = 0; e < 4; ++e) {
                  int i = row0 + tr * 16 + quad * 4 + e;
                  if (i < MM && j < MM)
                    slot[(i + 1) * 128 + (j + 1)] = f2bf_rne(acc4[tr][tc][e]);
                }
              }
            }
          }
          // g 5..7: idle
        }
      } else {
        // ------------- consumer -------------
        const int gap = per * 8 + g;
        if (!cons_active && cons_p < P_blk && gap >= cons_p * 8 + 5) {
          int a, b, sA, sB;
          decode_pair(B + cons_p * 512, a, b, sA, sB, cw_w);
          cslot = slots + (cons_p % NSLOT) * SLOT_U16;
          d1 = 1; cur1 = cur2 = np1 = np2 = 1.f;
          cons_active = 1;
        }
        if (cons_active) {
          int n = 254 - d1 + 1;
          if (n > QITER) n = QITER;
          const int l = lane;
          for (int it = 0; it < n; ++it, ++d1) {
            float nc1 = __shfl_up(cur1, 1);
            float c63 = __shfl(cur1, 63);
            float nc2 = __shfl_up(cur2, 1);
            if (l == 0) nc2 = c63;
            int r1 = d1 - l;      r1 = r1 < 0 ? 0 : (r1 > 127 ? 127 : r1);
            int r2 = d1 - l - 64; r2 = r2 < 0 ? 0 : (r2 > 127 ? 127 : r2);
            float m1 = __uint_as_float((unsigned int)cslot[r1 * 128 + l] << 16);
            float m2 = __uint_as_float((unsigned int)cslot[r2 * 128 + l + 64] << 16);
            float v1 = nc1 + cur1 + np1 * (m1 - 1.0f);
            float v2 = nc2 + cur2 + np2 * (m2 - 1.0f);
            if (l == 0) v1 = 1.0f;
            np1 = nc1; np2 = nc2;
            cur1 = v1; cur2 = v2;
          }
          if (d1 > 254) {
            if (l == 63) atomicAdd(acc, cw_w * cur2);   // K[127][127]
            cons_p += 4;
            cons_active = 0;
          }
        }
      }
    }
  }
}

__global__ void finalize_kernel(const float* __restrict__ acc,
                                unsigned int* __restrict__ out) {
  float v = acc[0];
  __hip_bfloat16 bv = __float2bfloat16(v);
  unsigned short u;
  __builtin_memcpy(&u, &bv, sizeof(u));
  out[0] = ((unsigned int)u << 16) | (unsigned int)u;
}

extern "C" void kernel_launch(void* const* d_in, const int* in_sizes, int n_in,
                              void* d_out, int out_size, void* d_ws, size_t ws_size,
                              hipStream_t stream) {
  const float* X = (const float*)d_in[0];
  const float* Y = (const float*)d_in[1];
  float* acc = (float*)d_ws;                                     // 4 B @ 0
  unsigned short* base = (unsigned short*)((char*)d_ws + 1024);  // 8 MB arrays

  prep_kernel<<<512, 256, 0, stream>>>(X, Y, base, acc);
  sig_fused_kernel<<<512, 512, 0, stream>>>(base, acc);
  finalize_kernel<<<1, 1, 0, stream>>>(acc, (unsigned int*)d_out);
}

// Round 6
// 460.380 us; speedup vs baseline: 1.4762x; 1.4762x over previous
//
#include <hip/hip_runtime.h>
#include <hip/hip_bf16.h>

#define MM 127
#define CHUNK_U16 4096        // per (matrix, k-chunk): 128 rows x 32 k = 8 KB
#define MAT_U16   16384       // 4 chunks per matrix
#define ARR_U16   1048576     // 64 matrices = 2 MB per array (Xhi/Xlo/Yhi/Ylo)
#define SLOT_U16  16384       // Mp slot [128][128] bf16 = 32 KB

typedef __attribute__((ext_vector_type(8))) short short8;
typedef __attribute__((ext_vector_type(4))) float floatx4;

__device__ __forceinline__ unsigned short f2bf_rne(float x) {
  unsigned int u = __float_as_uint(x);
  u += 0x7FFFu + ((u >> 16) & 1u);
  return (unsigned short)(u >> 16);
}

__device__ __forceinline__ void decode_pair(int p, int& a, int& b,
                                            int& srcA, int& srcB, float& w) {
  if (p < 4160) {
    srcA = 0;
    if (p >= 2080) { p -= 2080; srcA = 1; }
    srcB = srcA;
    int ia = (int)((sqrtf(8.0f * (float)p + 1.0f) - 1.0f) * 0.5f);
    while ((ia + 1) * (ia + 2) / 2 <= p) ia++;
    while (ia * (ia + 1) / 2 > p) ia--;
    b = p - ia * (ia + 1) / 2;
    a = ia;
    w = (a == b ? 1.0f : 2.0f) / 4096.0f;
  } else {
    p -= 4160;
    a = p >> 6; b = p & 63;
    srcA = 0; srcB = 1;
    w = -2.0f / 4096.0f;
  }
}

// ---- prep: increments -> hi/lo bf16 split, frag-image layout (R5-verified) ----
__global__ __launch_bounds__(256) void prep_kernel(
    const float* __restrict__ X, const float* __restrict__ Y,
    unsigned short* __restrict__ base, float* __restrict__ acc)
{
  if (blockIdx.x == 0 && threadIdx.x == 0) acc[0] = 0.f;
  const int bid = blockIdx.x;          // 0..511
  const int c = bid & 3;
  const int m = (bid >> 2) & 63;
  const int isY = bid >> 8;
  const float* src = (isY ? Y : X) + m * 128 * 128;
  unsigned short* dhi = base + isY * 2 * ARR_U16 + m * MAT_U16 + c * CHUNK_U16;
  unsigned short* dlo = dhi + ARR_U16;

  for (int s = threadIdx.x; s < 512; s += 256) {
    const int r = s >> 2;
    const int g = s & 3;
    uint4 hv = make_uint4(0, 0, 0, 0), lv = make_uint4(0, 0, 0, 0);
    if (r < MM) {
      const float* p = src + r * 128 + c * 32 + g * 8;
      float4 u0 = *reinterpret_cast<const float4*>(p);
      float4 u1 = *reinterpret_cast<const float4*>(p + 4);
      float4 v0 = *reinterpret_cast<const float4*>(p + 128);
      float4 v1 = *reinterpret_cast<const float4*>(p + 132);
      float d[8] = {v0.x - u0.x, v0.y - u0.y, v0.z - u0.z, v0.w - u0.w,
                    v1.x - u1.x, v1.y - u1.y, v1.z - u1.z, v1.w - u1.w};
      unsigned int hw[4], lw[4];
#pragma unroll
      for (int e = 0; e < 4; ++e) {
        unsigned int a0 = __float_as_uint(d[2 * e]);
        unsigned int a1 = __float_as_uint(d[2 * e + 1]);
        hw[e] = (a0 >> 16) | (a1 & 0xFFFF0000u);          // truncated-hi pair
        float r0 = d[2 * e]     - __uint_as_float(a0 & 0xFFFF0000u);
        float r1 = d[2 * e + 1] - __uint_as_float(a1 & 0xFFFF0000u);
        float2 rr; rr.x = r0; rr.y = r1;
        __hip_bfloat162 lp = __float22bfloat162_rn(rr);
        unsigned int lu; __builtin_memcpy(&lu, &lp, 4);
        lw[e] = lu;
      }
      hv = make_uint4(hw[0], hw[1], hw[2], hw[3]);
      lv = make_uint4(lw[0], lw[1], lw[2], lw[3]);
    }
    *reinterpret_cast<uint4*>(dhi + s * 8) = hv;
    *reinterpret_cast<uint4*>(dlo + s * 8) = lv;
  }
}

// ---- 4 pairs/block: 4 cooperative GEMMs -> 1 barrier -> 4 parallel PDEs ----
__global__ __launch_bounds__(256, 1) void sig_quad_kernel(
    const unsigned short* __restrict__ base, float* __restrict__ acc)
{
  extern __shared__ unsigned short slots[];   // 4 * 16384 u16 = 131,072 B dynamic
  const int tid = threadIdx.x;
  const int wid = tid >> 6, lane = tid & 63;
  const int lrow = lane & 15, quad = lane >> 4;
  const int row0 = (wid >> 1) * 64, col0 = (wid & 1) * 64;

  // ---- Phase 1: four sequential cooperative GEMMs (R5-verified math) ----
  for (int g = 0; g < 4; ++g) {
    int p = blockIdx.x * 4 + g;
    int a, b, sA, sB; float w_;
    decode_pair(p, a, b, sA, sB, w_);
    const unsigned short* Ah = base + sA * 2 * ARR_U16 + a * MAT_U16;
    const unsigned short* Bh = base + sB * 2 * ARR_U16 + b * MAT_U16;
    const unsigned short* Al = Ah + ARR_U16;
    const unsigned short* Bl = Bh + ARR_U16;

    floatx4 acc4[4][4];
#pragma unroll
    for (int tr = 0; tr < 4; ++tr)
#pragma unroll
      for (int tc = 0; tc < 4; ++tc) acc4[tr][tc] = (floatx4){0.f, 0.f, 0.f, 0.f};

    for (int c = 0; c < 4; ++c) {
      const unsigned short* gbh = Bh + c * CHUNK_U16;
      const unsigned short* gbl = Bl + c * CHUNK_U16;
      short8 bh[4], bl[4];
#pragma unroll
      for (int tc = 0; tc < 4; ++tc) {
        int off = (col0 + tc * 16 + lrow) * 32 + quad * 8;
        bh[tc] = *reinterpret_cast<const short8*>(gbh + off);
        bl[tc] = *reinterpret_cast<const short8*>(gbl + off);
      }
      const unsigned short* gah = Ah + c * CHUNK_U16;
      const unsigned short* gal = Al + c * CHUNK_U16;
#pragma unroll
      for (int tr = 0; tr < 4; ++tr) {
        int off = (row0 + tr * 16 + lrow) * 32 + quad * 8;
        short8 ah = *reinterpret_cast<const short8*>(gah + off);
        short8 al = *reinterpret_cast<const short8*>(gal + off);
#pragma unroll
        for (int tc = 0; tc < 4; ++tc) {
          acc4[tr][tc] = __builtin_amdgcn_mfma_f32_16x16x32_bf16(ah, bh[tc], acc4[tr][tc], 0, 0, 0);
          acc4[tr][tc] = __builtin_amdgcn_mfma_f32_16x16x32_bf16(ah, bl[tc], acc4[tr][tc], 0, 0, 0);
          acc4[tr][tc] = __builtin_amdgcn_mfma_f32_16x16x32_bf16(al, bh[tc], acc4[tr][tc], 0, 0, 0);
        }
      }
    }

    // epilogue: bordered Mp (bf16) into slot g.  Mp[i+1][j+1]=M[i][j]; row0/col0 = 0
    unsigned short* slot = slots + g * SLOT_U16;
    if (tid < 128) { slot[tid] = 0; slot[tid * 128] = 0; }
#pragma unroll
    for (int tr = 0; tr < 4; ++tr) {
#pragma unroll
      for (int tc = 0; tc < 4; ++tc) {
        int j = col0 + tc * 16 + lrow;
#pragma unroll
        for (int e = 0; e < 4; ++e) {
          int i = row0 + tr * 16 + quad * 4 + e;
          if (i < MM && j < MM)
            slot[(i + 1) * 128 + (j + 1)] = f2bf_rne(acc4[tr][tc][e]);
        }
      }
    }
  }
  __syncthreads();   // the only barrier: all slots complete

  // ---- Phase 2: per-wave PDE, lane l owns adjacent columns 2l, 2l+1 ----
  // cell (i,j) @ step d1=i+j: v = nc + cur + np*(Mp[i][j]-1); np = prior nc.
  // Odd col's west is in-lane (curE); even col's west via 1 shfl_up of curO.
  {
    int p = blockIdx.x * 4 + wid;
    int a, b, sA, sB; float w_;
    decode_pair(p, a, b, sA, sB, w_);
    const unsigned short* slot = slots + wid * SLOT_U16;
    const int l2 = lane * 2;

    float curE = 1.f, curO = 1.f, npE = 1.f, npO = 1.f;
#pragma unroll 2
    for (int d1 = 1; d1 <= 254; ++d1) {
      float ncE = __shfl_up(curO, 1);
      float ncO = curE;
      int rE = d1 - l2;
      int rO = rE - 1;
      rE = rE < 0 ? 0 : (rE > 127 ? 127 : rE);
      rO = rO < 0 ? 0 : (rO > 127 ? 127 : rO);
      float mE = __uint_as_float((unsigned int)slot[rE * 128 + l2] << 16);
      float mO = __uint_as_float((unsigned int)slot[rO * 128 + l2 + 1] << 16);
      float vE = ncE + curE + npE * (mE - 1.0f);
      float vO = ncO + curO + npO * (mO - 1.0f);
      if (lane == 0) vE = 1.0f;          // column 0 is the ones-column
      npE = ncE; npO = ncO;
      curE = vE; curO = vO;
    }
    if (lane == 63) atomicAdd(acc, w_ * curO);   // col 127 = odd col of lane 63
  }
}

__global__ void finalize_kernel(const float* __restrict__ acc,
                                unsigned int* __restrict__ out) {
  float v = acc[0];
  __hip_bfloat16 bv = __float2bfloat16(v);
  unsigned short u;
  __builtin_memcpy(&u, &bv, sizeof(u));
  out[0] = ((unsigned int)u << 16) | (unsigned int)u;
}

extern "C" void kernel_launch(void* const* d_in, const int* in_sizes, int n_in,
                              void* d_out, int out_size, void* d_ws, size_t ws_size,
                              hipStream_t stream) {
  const float* X = (const float*)d_in[0];
  const float* Y = (const float*)d_in[1];
  float* acc = (float*)d_ws;                                     // 4 B @ 0
  unsigned short* base = (unsigned short*)((char*)d_ws + 1024);  // 8 MB arrays

  // opt-in to 128 KB dynamic LDS (idempotent; host-side, capture-safe)
  hipFuncSetAttribute(reinterpret_cast<const void*>(sig_quad_kernel),
                      hipFuncAttributeMaxDynamicSharedMemorySize, 131072);

  prep_kernel<<<512, 256, 0, stream>>>(X, Y, base, acc);
  sig_quad_kernel<<<2064, 256, 131072, stream>>>(base, acc);
  finalize_kernel<<<1, 1, 0, stream>>>(acc, (unsigned int*)d_out);
}

// Round 7
// 285.160 us; speedup vs baseline: 2.3833x; 1.6145x over previous
//
#include <hip/hip_runtime.h>
#include <hip/hip_bf16.h>

#define MM 127
#define MPST 132              // bordered Mp row stride (u16)
#define CHUNK_U16 4096        // per (matrix, k-chunk): 512 slots * 8 u16 = 8 KB
#define MAT_U16   16384       // 4 chunks per matrix = 32 KB
#define ARR_U16   1048576     // 64 matrices = 2 MB per array (Xhi/Xlo/Yhi/Ylo)

typedef __attribute__((ext_vector_type(8))) short short8;
typedef __attribute__((ext_vector_type(4))) float floatx4;

__device__ __forceinline__ unsigned short f2bf_rne(float x) {
  unsigned int u = __float_as_uint(x);
  u += 0x7FFFu + ((u >> 16) & 1u);
  return (unsigned short)(u >> 16);
}

__device__ __forceinline__ void gload_lds16(const void* g, void* l) {
  __builtin_amdgcn_global_load_lds(
      (const __attribute__((address_space(1))) unsigned int*)g,
      (__attribute__((address_space(3))) unsigned int*)l, 16, 0, 0);
}

// ---- prep: increments -> hi/lo bf16 split, stored as the R4 LDS image ----
// slot(r,g) = r*4 + (g ^ (r&3));  element idx = slot*8 + e   (bank swizzle baked in)
__global__ __launch_bounds__(256) void prep_kernel(
    const float* __restrict__ X, const float* __restrict__ Y,
    unsigned short* __restrict__ base, float* __restrict__ acc)
{
  if (blockIdx.x == 0 && threadIdx.x == 0) acc[0] = 0.f;
  const int bid = blockIdx.x;          // 0..511
  const int c = bid & 3;
  const int m = (bid >> 2) & 63;
  const int isY = bid >> 8;
  const float* src = (isY ? Y : X) + m * 128 * 128;
  unsigned short* dhi = base + isY * 2 * ARR_U16 + m * MAT_U16 + c * CHUNK_U16;
  unsigned short* dlo = dhi + ARR_U16;

  for (int s = threadIdx.x; s < 512; s += 256) {
    const int r = s >> 2;
    const int g = (s & 3) ^ (r & 3);
    uint4 hv = make_uint4(0, 0, 0, 0), lv = make_uint4(0, 0, 0, 0);
    if (r < MM) {
      const float* p = src + r * 128 + c * 32 + g * 8;
      float4 u0 = *reinterpret_cast<const float4*>(p);
      float4 u1 = *reinterpret_cast<const float4*>(p + 4);
      float4 v0 = *reinterpret_cast<const float4*>(p + 128);
      float4 v1 = *reinterpret_cast<const float4*>(p + 132);
      float d[8] = {v0.x - u0.x, v0.y - u0.y, v0.z - u0.z, v0.w - u0.w,
                    v1.x - u1.x, v1.y - u1.y, v1.z - u1.z, v1.w - u1.w};
      unsigned int hw[4], lw[4];
#pragma unroll
      for (int e = 0; e < 4; ++e) {
        unsigned int a0 = __float_as_uint(d[2 * e]);
        unsigned int a1 = __float_as_uint(d[2 * e + 1]);
        hw[e] = (a0 >> 16) | (a1 & 0xFFFF0000u);          // truncated-hi pair
        float r0 = d[2 * e]     - __uint_as_float(a0 & 0xFFFF0000u);
        float r1 = d[2 * e + 1] - __uint_as_float(a1 & 0xFFFF0000u);
        float2 rr; rr.x = r0; rr.y = r1;
        __hip_bfloat162 lp = __float22bfloat162_rn(rr);
        unsigned int lu; __builtin_memcpy(&lu, &lp, 4);
        lw[e] = lu;
      }
      hv = make_uint4(hw[0], hw[1], hw[2], hw[3]);
      lv = make_uint4(lw[0], lw[1], lw[2], lw[3]);
    }
    *reinterpret_cast<uint4*>(dhi + s * 8) = hv;
    *reinterpret_cast<uint4*>(dlo + s * 8) = lv;
  }
}

__global__ __launch_bounds__(256, 4) void sig_pair_kernel(
    const unsigned short* __restrict__ base, float* __restrict__ acc)
{
  // LDS 33,792 B (4 blocks/CU). Staging chunk: Ahi@0, Alo@4096, Bhi@8192, Blo@12288 (u16).
  // After GEMM: bordered Mp[128][132] bf16 aliases the whole buffer.
  __shared__ unsigned short sm[16896];
  const int tid = threadIdx.x;
  const int bid = blockIdx.x;

  // ---- decode block -> (gram type, a, b, weight) ----
  float w;
  int a, b, srcA, srcB;
  if (bid < 4160) {
    int p = bid;
    srcA = 0;
    if (p >= 2080) { p -= 2080; srcA = 1; }
    srcB = srcA;
    int ia = (int)((sqrtf(8.0f * (float)p + 1.0f) - 1.0f) * 0.5f);
    while ((ia + 1) * (ia + 2) / 2 <= p) ia++;
    while (ia * (ia + 1) / 2 > p) ia--;
    int ib = p - ia * (ia + 1) / 2;
    a = ia; b = ib;
    w = (a == b ? 1.0f : 2.0f) / 4096.0f;
  } else {
    int p = bid - 4160;
    a = p >> 6; b = p & 63;
    srcA = 0; srcB = 1;
    w = -2.0f / 4096.0f;
  }
  const unsigned short* Ahi = base + srcA * 2 * ARR_U16 + a * MAT_U16;
  const unsigned short* Bhi = base + srcB * 2 * ARR_U16 + b * MAT_U16;
  const unsigned short* Alo = Ahi + ARR_U16;
  const unsigned short* Blo = Bhi + ARR_U16;

  const int wid = tid >> 6, lane = tid & 63;
  const int row0 = (wid >> 1) * 64, col0 = (wid & 1) * 64;
  const int lrow = lane & 15, quad = lane >> 4;

  // this wave's DMA part
  const unsigned short* gp = (wid == 0) ? Ahi : (wid == 1) ? Alo : (wid == 2) ? Bhi : Blo;
  const unsigned int ldsbase = wid * 4096;   // u16 index

  floatx4 acc4[4][4];
#pragma unroll
  for (int tr = 0; tr < 4; ++tr)
#pragma unroll
    for (int tc = 0; tc < 4; ++tc) acc4[tr][tc] = (floatx4){0.f, 0.f, 0.f, 0.f};

  for (int c = 0; c < 4; ++c) {
    __syncthreads();   // prior chunk's frag reads done before DMA overwrite
    const unsigned short* g = gp + c * CHUNK_U16 + lane * 8;
#pragma unroll
    for (int s = 0; s < 8; ++s)
      gload_lds16(g + s * 512, &sm[ldsbase + s * 512]);
    __syncthreads();   // DMA drained

    short8 bh[4], bl[4];
#pragma unroll
    for (int tc = 0; tc < 4; ++tc) {
      int r = col0 + tc * 16 + lrow;
      int off = r * 32 + ((quad ^ (r & 3)) * 8);
      bh[tc] = *reinterpret_cast<const short8*>(&sm[8192 + off]);
      bl[tc] = *reinterpret_cast<const short8*>(&sm[12288 + off]);
    }
#pragma unroll
    for (int tr = 0; tr < 4; ++tr) {
      int r = row0 + tr * 16 + lrow;
      int off = r * 32 + ((quad ^ (r & 3)) * 8);
      short8 ah = *reinterpret_cast<const short8*>(&sm[off]);
      short8 al = *reinterpret_cast<const short8*>(&sm[4096 + off]);
#pragma unroll
      for (int tc = 0; tc < 4; ++tc) {
        acc4[tr][tc] = __builtin_amdgcn_mfma_f32_16x16x32_bf16(ah, bh[tc], acc4[tr][tc], 0, 0, 0);
        acc4[tr][tc] = __builtin_amdgcn_mfma_f32_16x16x32_bf16(ah, bl[tc], acc4[tr][tc], 0, 0, 0);
        acc4[tr][tc] = __builtin_amdgcn_mfma_f32_16x16x32_bf16(al, bh[tc], acc4[tr][tc], 0, 0, 0);
      }
    }
  }
  __syncthreads();   // staging reads done; alias Mp over the buffer

  // ---- bordered Mp (bf16): Mp[i+1][j+1] = M[i][j]; row 0 / col 0 = 0 ----
  if (tid < MPST) sm[tid] = 0;
  if (tid < 128) sm[tid * MPST] = 0;
#pragma unroll
  for (int tr = 0; tr < 4; ++tr) {
#pragma unroll
    for (int tc = 0; tc < 4; ++tc) {
      int j = col0 + tc * 16 + lrow;
#pragma unroll
      for (int e = 0; e < 4; ++e) {
        int i = row0 + tr * 16 + quad * 4 + e;
        if (i < MM && j < MM)
          sm[(i + 1) * MPST + (j + 1)] = f2bf_rne(acc4[tr][tc][e]);
      }
    }
  }
  __syncthreads();

  // ---- Phase 2: 2-col-per-lane PDE (R6-verified recurrence), wave 0 ----
  // lane l owns cols 2l, 2l+1. Per iter: 1 shfl; m-reads prefetched a group
  // of 4 iterations ahead so ds_reads leave the dependency chain.
  if (tid < 64) {
    const int l = tid;
    const int l2 = l * 2;
    float curE = 1.f, curO = 1.f, npE = 1.f, npO = 1.f;
    float pmE[4], pmO[4];
    // preload group 0 (d1 = 1..4)
#pragma unroll
    for (int e = 0; e < 4; ++e) {
      int rE = 1 + e - l2; rE = rE < 0 ? 0 : (rE > 127 ? 127 : rE);
      int rO = e - l2;     rO = rO < 0 ? 0 : (rO > 127 ? 127 : rO);
      pmE[e] = __uint_as_float((unsigned int)sm[rE * MPST + l2] << 16);
      pmO[e] = __uint_as_float((unsigned int)sm[rO * MPST + l2 + 1] << 16);
    }
    for (int g = 0; g < 63; ++g) {         // groups cover d1 = 1..252
      float cmE[4], cmO[4];
#pragma unroll
      for (int e = 0; e < 4; ++e) { cmE[e] = pmE[e]; cmO[e] = pmO[e]; }
      if (g < 62) {
        const int db = 5 + 4 * g;          // next group's base d1
#pragma unroll
        for (int e = 0; e < 4; ++e) {
          int rE = db + e - l2;     rE = rE < 0 ? 0 : (rE > 127 ? 127 : rE);
          int rO = db + e - 1 - l2; rO = rO < 0 ? 0 : (rO > 127 ? 127 : rO);
          pmE[e] = __uint_as_float((unsigned int)sm[rE * MPST + l2] << 16);
          pmO[e] = __uint_as_float((unsigned int)sm[rO * MPST + l2 + 1] << 16);
        }
      }
#pragma unroll
      for (int e = 0; e < 4; ++e) {
        float ncE = __shfl_up(curO, 1);
        float ncO = curE;
        float vE = ncE + curE + npE * (cmE[e] - 1.0f);
        float vO = ncO + curO + npO * (cmO[e] - 1.0f);
        if (l == 0) vE = 1.0f;             // column 0 is the ones-column
        npE = ncE; npO = ncO;
        curE = vE; curO = vO;
      }
    }
    // tail: d1 = 253, 254
    for (int d1 = 253; d1 <= 254; ++d1) {
      int rE = d1 - l2;     rE = rE < 0 ? 0 : (rE > 127 ? 127 : rE);
      int rO = d1 - 1 - l2; rO = rO < 0 ? 0 : (rO > 127 ? 127 : rO);
      float mE = __uint_as_float((unsigned int)sm[rE * MPST + l2] << 16);
      float mO = __uint_as_float((unsigned int)sm[rO * MPST + l2 + 1] << 16);
      float ncE = __shfl_up(curO, 1);
      float ncO = curE;
      float vE = ncE + curE + npE * (mE - 1.0f);
      float vO = ncO + curO + npO * (mO - 1.0f);
      if (l == 0) vE = 1.0f;
      npE = ncE; npO = ncO;
      curE = vE; curO = vO;
    }
    if (l == 63) atomicAdd(acc, w * curO);   // col 127 = odd col of lane 63
  }
}

__global__ void finalize_kernel(const float* __restrict__ acc,
                                unsigned int* __restrict__ out) {
  float v = acc[0];
  __hip_bfloat16 bv = __float2bfloat16(v);
  unsigned short u;
  __builtin_memcpy(&u, &bv, sizeof(u));
  out[0] = ((unsigned int)u << 16) | (unsigned int)u;
}

extern "C" void kernel_launch(void* const* d_in, const int* in_sizes, int n_in,
                              void* d_out, int out_size, void* d_ws, size_t ws_size,
                              hipStream_t stream) {
  const float* X = (const float*)d_in[0];
  const float* Y = (const float*)d_in[1];
  float* acc = (float*)d_ws;                                     // 4 B @ 0
  unsigned short* base = (unsigned short*)((char*)d_ws + 1024);  // 8 MB arrays

  prep_kernel<<<512, 256, 0, stream>>>(X, Y, base, acc);
  sig_pair_kernel<<<8256, 256, 0, stream>>>(base, acc);
  finalize_kernel<<<1, 1, 0, stream>>>(acc, (unsigned int*)d_out);
}

// Round 8
// 277.277 us; speedup vs baseline: 2.4510x; 1.0284x over previous
//
#include <hip/hip_runtime.h>
#include <hip/hip_bf16.h>

#define MM 127
#define MPST 132              // bordered Mp row stride (u16)
#define CHUNK_U16 4096        // per (matrix, k-chunk): 512 slots * 8 u16 = 8 KB
#define MAT_U16   16384       // 4 chunks per matrix = 32 KB
#define ARR_U16   1048576     // 64 matrices = 2 MB per array (Xhi/Xlo/Yhi/Ylo)

typedef __attribute__((ext_vector_type(8))) short short8;
typedef __attribute__((ext_vector_type(4))) float floatx4;

__device__ __forceinline__ unsigned short f2bf_rne(float x) {
  unsigned int u = __float_as_uint(x);
  u += 0x7FFFu + ((u >> 16) & 1u);
  return (unsigned short)(u >> 16);
}

__device__ __forceinline__ void gload_lds16(const void* g, void* l) {
  __builtin_amdgcn_global_load_lds(
      (const __attribute__((address_space(1))) unsigned int*)g,
      (__attribute__((address_space(3))) unsigned int*)l, 16, 0, 0);
}

// ---- prep: increments -> hi/lo bf16 split, stored as the R4 LDS image ----
// slot(r,g) = r*4 + (g ^ (r&3));  element idx = slot*8 + e   (bank swizzle baked in)
__global__ __launch_bounds__(256) void prep_kernel(
    const float* __restrict__ X, const float* __restrict__ Y,
    unsigned short* __restrict__ base, float* __restrict__ acc)
{
  if (blockIdx.x == 0 && threadIdx.x == 0) acc[0] = 0.f;
  const int bid = blockIdx.x;          // 0..511
  const int c = bid & 3;
  const int m = (bid >> 2) & 63;
  const int isY = bid >> 8;
  const float* src = (isY ? Y : X) + m * 128 * 128;
  unsigned short* dhi = base + isY * 2 * ARR_U16 + m * MAT_U16 + c * CHUNK_U16;
  unsigned short* dlo = dhi + ARR_U16;

  for (int s = threadIdx.x; s < 512; s += 256) {
    const int r = s >> 2;
    const int g = (s & 3) ^ (r & 3);
    uint4 hv = make_uint4(0, 0, 0, 0), lv = make_uint4(0, 0, 0, 0);
    if (r < MM) {
      const float* p = src + r * 128 + c * 32 + g * 8;
      float4 u0 = *reinterpret_cast<const float4*>(p);
      float4 u1 = *reinterpret_cast<const float4*>(p + 4);
      float4 v0 = *reinterpret_cast<const float4*>(p + 128);
      float4 v1 = *reinterpret_cast<const float4*>(p + 132);
      float d[8] = {v0.x - u0.x, v0.y - u0.y, v0.z - u0.z, v0.w - u0.w,
                    v1.x - u1.x, v1.y - u1.y, v1.z - u1.z, v1.w - u1.w};
      unsigned int hw[4], lw[4];
#pragma unroll
      for (int e = 0; e < 4; ++e) {
        unsigned int a0 = __float_as_uint(d[2 * e]);
        unsigned int a1 = __float_as_uint(d[2 * e + 1]);
        hw[e] = (a0 >> 16) | (a1 & 0xFFFF0000u);          // truncated-hi pair
        float r0 = d[2 * e]     - __uint_as_float(a0 & 0xFFFF0000u);
        float r1 = d[2 * e + 1] - __uint_as_float(a1 & 0xFFFF0000u);
        float2 rr; rr.x = r0; rr.y = r1;
        __hip_bfloat162 lp = __float22bfloat162_rn(rr);
        unsigned int lu; __builtin_memcpy(&lu, &lp, 4);
        lw[e] = lu;
      }
      hv = make_uint4(hw[0], hw[1], hw[2], hw[3]);
      lv = make_uint4(lw[0], lw[1], lw[2], lw[3]);
    }
    *reinterpret_cast<uint4*>(dhi + s * 8) = hv;
    *reinterpret_cast<uint4*>(dlo + s * 8) = lv;
  }
}

__global__ __launch_bounds__(256, 4) void sig_pair_kernel(
    const unsigned short* __restrict__ base, float* __restrict__ acc)
{
  // LDS 33,792 B (4 blocks/CU). Staging chunk: Ahi@0, Alo@4096, Bhi@8192, Blo@12288 (u16).
  // After GEMM: bordered Mp[128][132] bf16 aliases the whole buffer.
  __shared__ unsigned short sm[16896];
  const int tid = threadIdx.x;
  const int bid = blockIdx.x;

  // ---- decode block -> (gram type, a, b, weight) ----
  float w;
  int a, b, srcA, srcB;
  if (bid < 4160) {
    int p = bid;
    srcA = 0;
    if (p >= 2080) { p -= 2080; srcA = 1; }
    srcB = srcA;
    int ia = (int)((sqrtf(8.0f * (float)p + 1.0f) - 1.0f) * 0.5f);
    while ((ia + 1) * (ia + 2) / 2 <= p) ia++;
    while (ia * (ia + 1) / 2 > p) ia--;
    int ib = p - ia * (ia + 1) / 2;
    a = ia; b = ib;
    w = (a == b ? 1.0f : 2.0f) / 4096.0f;
  } else {
    int p = bid - 4160;
    a = p >> 6; b = p & 63;
    srcA = 0; srcB = 1;
    w = -2.0f / 4096.0f;
  }
  const unsigned short* Ahi = base + srcA * 2 * ARR_U16 + a * MAT_U16;
  const unsigned short* Bhi = base + srcB * 2 * ARR_U16 + b * MAT_U16;
  const unsigned short* Alo = Ahi + ARR_U16;
  const unsigned short* Blo = Bhi + ARR_U16;

  const int wid = tid >> 6, lane = tid & 63;
  const int row0 = (wid >> 1) * 64, col0 = (wid & 1) * 64;
  const int lrow = lane & 15, quad = lane >> 4;

  // this wave's DMA part
  const unsigned short* gp = (wid == 0) ? Ahi : (wid == 1) ? Alo : (wid == 2) ? Bhi : Blo;
  const unsigned int ldsbase = wid * 4096;   // u16 index

  floatx4 acc4[4][4];
#pragma unroll
  for (int tr = 0; tr < 4; ++tr)
#pragma unroll
    for (int tc = 0; tc < 4; ++tc) acc4[tr][tc] = (floatx4){0.f, 0.f, 0.f, 0.f};

  for (int c = 0; c < 4; ++c) {
    __syncthreads();   // prior chunk's frag reads done before DMA overwrite
    const unsigned short* g = gp + c * CHUNK_U16 + lane * 8;
#pragma unroll
    for (int s = 0; s < 8; ++s)
      gload_lds16(g + s * 512, &sm[ldsbase + s * 512]);
    __syncthreads();   // DMA drained

    // two half-passes over B tiles: only 2 B-frag pairs live at a time
    // (keeps total regs ~110 < 128 so no scratch spill at 4 waves/SIMD)
#pragma unroll
    for (int th = 0; th < 2; ++th) {
      short8 bh[2], bl[2];
#pragma unroll
      for (int tc = 0; tc < 2; ++tc) {
        int r = col0 + (th * 2 + tc) * 16 + lrow;
        int off = r * 32 + ((quad ^ (r & 3)) * 8);
        bh[tc] = *reinterpret_cast<const short8*>(&sm[8192 + off]);
        bl[tc] = *reinterpret_cast<const short8*>(&sm[12288 + off]);
      }
#pragma unroll
      for (int tr = 0; tr < 4; ++tr) {
        int r = row0 + tr * 16 + lrow;
        int off = r * 32 + ((quad ^ (r & 3)) * 8);
        short8 ah = *reinterpret_cast<const short8*>(&sm[off]);
        short8 al = *reinterpret_cast<const short8*>(&sm[4096 + off]);
#pragma unroll
        for (int tc = 0; tc < 2; ++tc) {
          int cc = th * 2 + tc;
          acc4[tr][cc] = __builtin_amdgcn_mfma_f32_16x16x32_bf16(ah, bh[tc], acc4[tr][cc], 0, 0, 0);
          acc4[tr][cc] = __builtin_amdgcn_mfma_f32_16x16x32_bf16(ah, bl[tc], acc4[tr][cc], 0, 0, 0);
          acc4[tr][cc] = __builtin_amdgcn_mfma_f32_16x16x32_bf16(al, bh[tc], acc4[tr][cc], 0, 0, 0);
        }
      }
    }
  }
  __syncthreads();   // staging reads done; alias Mp over the buffer

  // ---- bordered Mp (bf16): Mp[i+1][j+1] = M[i][j]; row 0 / col 0 = 0 ----
  if (tid < MPST) sm[tid] = 0;
  if (tid < 128) sm[tid * MPST] = 0;
#pragma unroll
  for (int tr = 0; tr < 4; ++tr) {
#pragma unroll
    for (int tc = 0; tc < 4; ++tc) {
      int j = col0 + tc * 16 + lrow;
#pragma unroll
      for (int e = 0; e < 4; ++e) {
        int i = row0 + tr * 16 + quad * 4 + e;
        if (i < MM && j < MM)
          sm[(i + 1) * MPST + (j + 1)] = f2bf_rne(acc4[tr][tc][e]);
      }
    }
  }
  __syncthreads();

  // ---- Phase 2: 2-col-per-lane PDE (R7-verified), on wave (bid & 3) ----
  // Spreading the PDE wave across blocks avoids all resident blocks'
  // PDEs serializing on SIMD 0 (waves map round-robin to SIMDs).
  if (wid == (bid & 3)) {
    const int l = lane;
    const int l2 = l * 2;
    float curE = 1.f, curO = 1.f, npE = 1.f, npO = 1.f;
    float pmE[4], pmO[4];    // hold (m - 1), computed off the critical chain
    // preload group 0 (d1 = 1..4)
#pragma unroll
    for (int e = 0; e < 4; ++e) {
      int rE = 1 + e - l2; rE = rE < 0 ? 0 : (rE > 127 ? 127 : rE);
      int rO = e - l2;     rO = rO < 0 ? 0 : (rO > 127 ? 127 : rO);
      pmE[e] = __uint_as_float((unsigned int)sm[rE * MPST + l2] << 16) - 1.0f;
      pmO[e] = __uint_as_float((unsigned int)sm[rO * MPST + l2 + 1] << 16) - 1.0f;
    }
    for (int g = 0; g < 63; ++g) {         // groups cover d1 = 1..252
      float cmE[4], cmO[4];
#pragma unroll
      for (int e = 0; e < 4; ++e) { cmE[e] = pmE[e]; cmO[e] = pmO[e]; }
      if (g < 62) {
        const int db = 5 + 4 * g;          // next group's base d1
#pragma unroll
        for (int e = 0; e < 4; ++e) {
          int rE = db + e - l2;     rE = rE < 0 ? 0 : (rE > 127 ? 127 : rE);
          int rO = db + e - 1 - l2; rO = rO < 0 ? 0 : (rO > 127 ? 127 : rO);
          pmE[e] = __uint_as_float((unsigned int)sm[rE * MPST + l2] << 16) - 1.0f;
          pmO[e] = __uint_as_float((unsigned int)sm[rO * MPST + l2 + 1] << 16) - 1.0f;
        }
      }
#pragma unroll
      for (int e = 0; e < 4; ++e) {
        float ncE = __shfl_up(curO, 1);
        float ncO = curE;
        float vE = ncE + curE + npE * cmE[e];
        float vO = ncO + curO + npO * cmO[e];
        if (l == 0) vE = 1.0f;             // column 0 is the ones-column
        npE = ncE; npO = ncO;
        curE = vE; curO = vO;
      }
    }
    // tail: d1 = 253, 254
    for (int d1 = 253; d1 <= 254; ++d1) {
      int rE = d1 - l2;     rE = rE < 0 ? 0 : (rE > 127 ? 127 : rE);
      int rO = d1 - 1 - l2; rO = rO < 0 ? 0 : (rO > 127 ? 127 : rO);
      float mE = __uint_as_float((unsigned int)sm[rE * MPST + l2] << 16) - 1.0f;
      float mO = __uint_as_float((unsigned int)sm[rO * MPST + l2 + 1] << 16) - 1.0f;
      float ncE = __shfl_up(curO, 1);
      float ncO = curE;
      float vE = ncE + curE + npE * mE;
      float vO = ncO + curO + npO * mO;
      if (l == 0) vE = 1.0f;
      npE = ncE; npO = ncO;
      curE = vE; curO = vO;
    }
    if (l == 63) atomicAdd(acc, w * curO);   // col 127 = odd col of lane 63
  }
}

__global__ void finalize_kernel(const float* __restrict__ acc,
                                unsigned int* __restrict__ out) {
  float v = acc[0];
  __hip_bfloat16 bv = __float2bfloat16(v);
  unsigned short u;
  __builtin_memcpy(&u, &bv, sizeof(u));
  out[0] = ((unsigned int)u << 16) | (unsigned int)u;
}

extern "C" void kernel_launch(void* const* d_in, const int* in_sizes, int n_in,
                              void* d_out, int out_size, void* d_ws, size_t ws_size,
                              hipStream_t stream) {
  const float* X = (const float*)d_in[0];
  const float* Y = (const float*)d_in[1];
  float* acc = (float*)d_ws;                                     // 4 B @ 0
  unsigned short* base = (unsigned short*)((char*)d_ws + 1024);  // 8 MB arrays

  prep_kernel<<<512, 256, 0, stream>>>(X, Y, base, acc);
  sig_pair_kernel<<<8256, 256, 0, stream>>>(base, acc);
  finalize_kernel<<<1, 1, 0, stream>>>(acc, (unsigned int*)d_out);
}

// Round 9
// 246.599 us; speedup vs baseline: 2.7560x; 1.1244x over previous
//
#include <hip/hip_runtime.h>
#include <hip/hip_bf16.h>

#define MM 127
#define MPST 132              // bordered Mp row stride (u16)
#define CHUNK_U16 4096        // per (matrix, k-chunk): 512 slots * 8 u16 = 8 KB
#define MAT_U16   16384       // 4 chunks per matrix = 32 KB
#define ARR_U16   1048576     // 64 matrices = 2 MB per array (X, Y)

typedef __attribute__((ext_vector_type(8))) short short8;
typedef __attribute__((ext_vector_type(4))) float floatx4;

__device__ __forceinline__ unsigned short f2bf_rne(float x) {
  unsigned int u = __float_as_uint(x);
  u += 0x7FFFu + ((u >> 16) & 1u);
  return (unsigned short)(u >> 16);
}

__device__ __forceinline__ void gload_lds16(const void* g, void* l) {
  __builtin_amdgcn_global_load_lds(
      (const __attribute__((address_space(1))) unsigned int*)g,
      (__attribute__((address_space(3))) unsigned int*)l, 16, 0, 0);
}

// ---- prep: increments -> RNE bf16, stored as the LDS frag image ----
// slot(r,g) = r*4 + (g ^ (r&3));  element idx = slot*8 + e  (bank swizzle baked in)
__global__ __launch_bounds__(256) void prep_kernel(
    const float* __restrict__ X, const float* __restrict__ Y,
    unsigned short* __restrict__ base, float* __restrict__ acc)
{
  if (blockIdx.x == 0 && threadIdx.x == 0) acc[0] = 0.f;
  const int bid = blockIdx.x;          // 0..255
  const int c = bid & 3;
  const int m = (bid >> 2) & 63;
  const int isY = bid >> 8;            // grid is 512: 0..255 X, 256..511 Y
  const float* src = (isY ? Y : X) + m * 128 * 128;
  unsigned short* dst = base + isY * ARR_U16 + m * MAT_U16 + c * CHUNK_U16;

  for (int s = threadIdx.x; s < 512; s += 256) {
    const int r = s >> 2;
    const int g = (s & 3) ^ (r & 3);
    uint4 hv = make_uint4(0, 0, 0, 0);
    if (r < MM) {
      const float* p = src + r * 128 + c * 32 + g * 8;
      float4 u0 = *reinterpret_cast<const float4*>(p);
      float4 u1 = *reinterpret_cast<const float4*>(p + 4);
      float4 v0 = *reinterpret_cast<const float4*>(p + 128);
      float4 v1 = *reinterpret_cast<const float4*>(p + 132);
      float d[8] = {v0.x - u0.x, v0.y - u0.y, v0.z - u0.z, v0.w - u0.w,
                    v1.x - u1.x, v1.y - u1.y, v1.z - u1.z, v1.w - u1.w};
      unsigned int hw[4];
#pragma unroll
      for (int e = 0; e < 4; ++e) {
        float2 rr; rr.x = d[2 * e]; rr.y = d[2 * e + 1];
        __hip_bfloat162 hp = __float22bfloat162_rn(rr);   // v_cvt_pk_bf16_f32
        unsigned int hu; __builtin_memcpy(&hu, &hp, 4);
        hw[e] = hu;
      }
      hv = make_uint4(hw[0], hw[1], hw[2], hw[3]);
    }
    *reinterpret_cast<uint4*>(dst + s * 8) = hv;
  }
}

__global__ __launch_bounds__(256, 4) void sig_pair_kernel(
    const unsigned short* __restrict__ base, float* __restrict__ acc)
{
  // LDS 33,792 B (4 blocks/CU). Staging chunk (16 KB): A@0, B@4096 (u16 idx).
  // After GEMM: bordered Mp[128][132] bf16 aliases the whole buffer.
  __shared__ unsigned short sm[16896];
  const int tid = threadIdx.x;
  const int bid = blockIdx.x;

  // ---- decode block -> (gram type, a, b, weight) ----
  float w;
  int a, b, srcA, srcB;
  if (bid < 4160) {
    int p = bid;
    srcA = 0;
    if (p >= 2080) { p -= 2080; srcA = 1; }
    srcB = srcA;
    int ia = (int)((sqrtf(8.0f * (float)p + 1.0f) - 1.0f) * 0.5f);
    while ((ia + 1) * (ia + 2) / 2 <= p) ia++;
    while (ia * (ia + 1) / 2 > p) ia--;
    int ib = p - ia * (ia + 1) / 2;
    a = ia; b = ib;
    w = (a == b ? 1.0f : 2.0f) / 4096.0f;
  } else {
    int p = bid - 4160;
    a = p >> 6; b = p & 63;
    srcA = 0; srcB = 1;
    w = -2.0f / 4096.0f;
  }
  const unsigned short* Am = base + srcA * ARR_U16 + a * MAT_U16;
  const unsigned short* Bm = base + srcB * ARR_U16 + b * MAT_U16;

  const int wid = tid >> 6, lane = tid & 63;
  const int row0 = (wid >> 1) * 64, col0 = (wid & 1) * 64;
  const int lrow = lane & 15, quad = lane >> 4;

  // this wave's DMA quarter: waves 0,1 -> A halves; waves 2,3 -> B halves
  const unsigned short* gp = ((wid < 2) ? Am : Bm) + (wid & 1) * 2048;
  const unsigned int ldsbase = wid * 2048;   // u16 index

  floatx4 acc4[4][4];
#pragma unroll
  for (int tr = 0; tr < 4; ++tr)
#pragma unroll
    for (int tc = 0; tc < 4; ++tc) acc4[tr][tc] = (floatx4){0.f, 0.f, 0.f, 0.f};

  for (int c = 0; c < 4; ++c) {
    __syncthreads();   // prior chunk's frag reads done before DMA overwrite
    const unsigned short* g = gp + c * CHUNK_U16 + lane * 8;
#pragma unroll
    for (int s = 0; s < 4; ++s)
      gload_lds16(g + s * 512, &sm[ldsbase + s * 512]);
    __syncthreads();   // DMA drained

    short8 bh[4];
#pragma unroll
    for (int tc = 0; tc < 4; ++tc) {
      int r = col0 + tc * 16 + lrow;
      int off = r * 32 + ((quad ^ (r & 3)) * 8);
      bh[tc] = *reinterpret_cast<const short8*>(&sm[4096 + off]);
    }
#pragma unroll
    for (int tr = 0; tr < 4; ++tr) {
      int r = row0 + tr * 16 + lrow;
      int off = r * 32 + ((quad ^ (r & 3)) * 8);
      short8 ah = *reinterpret_cast<const short8*>(&sm[off]);
#pragma unroll
      for (int tc = 0; tc < 4; ++tc)
        acc4[tr][tc] = __builtin_amdgcn_mfma_f32_16x16x32_bf16(ah, bh[tc], acc4[tr][tc], 0, 0, 0);
    }
  }
  __syncthreads();   // staging reads done; alias Mp over the buffer

  // ---- bordered Mp (bf16): Mp[i+1][j+1] = M[i][j]; row 0 / col 0 = 0 ----
  if (tid < MPST) sm[tid] = 0;
  if (tid < 128) sm[tid * MPST] = 0;
#pragma unroll
  for (int tr = 0; tr < 4; ++tr) {
#pragma unroll
    for (int tc = 0; tc < 4; ++tc) {
      int j = col0 + tc * 16 + lrow;
#pragma unroll
      for (int e = 0; e < 4; ++e) {
        int i = row0 + tr * 16 + quad * 4 + e;
        if (i < MM && j < MM)
          sm[(i + 1) * MPST + (j + 1)] = f2bf_rne(acc4[tr][tc][e]);
      }
    }
  }
  __syncthreads();

  // ---- Phase 2: 2-col-per-lane PDE (R7/R8-verified), on wave (bid & 3) ----
  if (wid == (bid & 3)) {
    const int l = lane;
    const int l2 = l * 2;
    float curE = 1.f, curO = 1.f, npE = 1.f, npO = 1.f;
    float pmE[4], pmO[4];    // hold (m - 1), computed off the critical chain
    // preload group 0 (d1 = 1..4)
#pragma unroll
    for (int e = 0; e < 4; ++e) {
      int rE = 1 + e - l2; rE = rE < 0 ? 0 : (rE > 127 ? 127 : rE);
      int rO = e - l2;     rO = rO < 0 ? 0 : (rO > 127 ? 127 : rO);
      pmE[e] = __uint_as_float((unsigned int)sm[rE * MPST + l2] << 16) - 1.0f;
      pmO[e] = __uint_as_float((unsigned int)sm[rO * MPST + l2 + 1] << 16) - 1.0f;
    }
    for (int g = 0; g < 63; ++g) {         // groups cover d1 = 1..252
      float cmE[4], cmO[4];
#pragma unroll
      for (int e = 0; e < 4; ++e) { cmE[e] = pmE[e]; cmO[e] = pmO[e]; }
      if (g < 62) {
        const int db = 5 + 4 * g;          // next group's base d1
#pragma unroll
        for (int e = 0; e < 4; ++e) {
          int rE = db + e - l2;     rE = rE < 0 ? 0 : (rE > 127 ? 127 : rE);
          int rO = db + e - 1 - l2; rO = rO < 0 ? 0 : (rO > 127 ? 127 : rO);
          pmE[e] = __uint_as_float((unsigned int)sm[rE * MPST + l2] << 16) - 1.0f;
          pmO[e] = __uint_as_float((unsigned int)sm[rO * MPST + l2 + 1] << 16) - 1.0f;
        }
      }
#pragma unroll
      for (int e = 0; e < 4; ++e) {
        float ncE = __shfl_up(curO, 1);
        float ncO = curE;
        float vE = ncE + curE + npE * cmE[e];
        float vO = ncO + curO + npO * cmO[e];
        if (l == 0) vE = 1.0f;             // column 0 is the ones-column
        npE = ncE; npO = ncO;
        curE = vE; curO = vO;
      }
    }
    // tail: d1 = 253, 254
    for (int d1 = 253; d1 <= 254; ++d1) {
      int rE = d1 - l2;     rE = rE < 0 ? 0 : (rE > 127 ? 127 : rE);
      int rO = d1 - 1 - l2; rO = rO < 0 ? 0 : (rO > 127 ? 127 : rO);
      float mE = __uint_as_float((unsigned int)sm[rE * MPST + l2] << 16) - 1.0f;
      float mO = __uint_as_float((unsigned int)sm[rO * MPST + l2 + 1] << 16) - 1.0f;
      float ncE = __shfl_up(curO, 1);
      float ncO = curE;
      float vE = ncE + curE + npE * mE;
      float vO = ncO + curO + npO * mO;
      if (l == 0) vE = 1.0f;
      npE = ncE; npO = ncO;
      curE = vE; curO = vO;
    }
    if (l == 63) atomicAdd(acc, w * curO);   // col 127 = odd col of lane 63
  }
}

__global__ void finalize_kernel(const float* __restrict__ acc,
                                unsigned int* __restrict__ out) {
  float v = acc[0];
  __hip_bfloat16 bv = __float2bfloat16(v);
  unsigned short u;
  __builtin_memcpy(&u, &bv, sizeof(u));
  out[0] = ((unsigned int)u << 16) | (unsigned int)u;
}

extern "C" void kernel_launch(void* const* d_in, const int* in_sizes, int n_in,
                              void* d_out, int out_size, void* d_ws, size_t ws_size,
                              hipStream_t stream) {
  const float* X = (const float*)d_in[0];
  const float* Y = (const float*)d_in[1];
  float* acc = (float*)d_ws;                                     // 4 B @ 0
  unsigned short* base = (unsigned short*)((char*)d_ws + 1024);  // 4 MB arrays

  prep_kernel<<<512, 256, 0, stream>>>(X, Y, base, acc);
  sig_pair_kernel<<<8256, 256, 0, stream>>>(base, acc);
  finalize_kernel<<<1, 1, 0, stream>>>(acc, (unsigned int*)d_out);
}

// Round 10
// 204.693 us; speedup vs baseline: 3.3202x; 1.2047x over previous
//
#include <hip/hip_runtime.h>
#include <hip/hip_bf16.h>

#define MM 127
#define CHUNK_U16 4096        // per (matrix, k-chunk): 512 slots * 8 u16 = 8 KB
#define MAT_U16   16384       // 4 chunks per matrix = 32 KB
#define ARR_U16   1048576     // 64 matrices = 2 MB per array (X, Y)

typedef __attribute__((ext_vector_type(8))) short short8;
typedef __attribute__((ext_vector_type(4))) float floatx4;

__device__ __forceinline__ unsigned short f2bf_rne(float x) {
  unsigned int u = __float_as_uint(x);
  u += 0x7FFFu + ((u >> 16) & 1u);
  return (unsigned short)(u >> 16);
}

__device__ __forceinline__ void gload_lds16(const void* g, void* l) {
  __builtin_amdgcn_global_load_lds(
      (const __attribute__((address_space(1))) unsigned int*)g,
      (__attribute__((address_space(3))) unsigned int*)l, 16, 0, 0);
}

// wave_shr:1 via DPP: lane l gets lane l-1's value; lane 0 gets 0 (bound_ctrl)
__device__ __forceinline__ float wave_shr1(float x) {
  return __int_as_float(__builtin_amdgcn_update_dpp(
      0, __float_as_int(x), 0x138, 0xf, 0xf, true));
}

// ---- prep: increments -> RNE bf16, stored as the LDS frag image (R9-verified) ----
__global__ __launch_bounds__(256) void prep_kernel(
    const float* __restrict__ X, const float* __restrict__ Y,
    unsigned short* __restrict__ base, float* __restrict__ acc)
{
  if (blockIdx.x == 0 && threadIdx.x == 0) acc[0] = 0.f;
  const int bid = blockIdx.x;
  const int c = bid & 3;
  const int m = (bid >> 2) & 63;
  const int isY = bid >> 8;
  const float* src = (isY ? Y : X) + m * 128 * 128;
  unsigned short* dst = base + isY * ARR_U16 + m * MAT_U16 + c * CHUNK_U16;

  for (int s = threadIdx.x; s < 512; s += 256) {
    const int r = s >> 2;
    const int g = (s & 3) ^ (r & 3);
    uint4 hv = make_uint4(0, 0, 0, 0);
    if (r < MM) {
      const float* p = src + r * 128 + c * 32 + g * 8;
      float4 u0 = *reinterpret_cast<const float4*>(p);
      float4 u1 = *reinterpret_cast<const float4*>(p + 4);
      float4 v0 = *reinterpret_cast<const float4*>(p + 128);
      float4 v1 = *reinterpret_cast<const float4*>(p + 132);
      float d[8] = {v0.x - u0.x, v0.y - u0.y, v0.z - u0.z, v0.w - u0.w,
                    v1.x - u1.x, v1.y - u1.y, v1.z - u1.z, v1.w - u1.w};
      unsigned int hw[4];
#pragma unroll
      for (int e = 0; e < 4; ++e) {
        float2 rr; rr.x = d[2 * e]; rr.y = d[2 * e + 1];
        __hip_bfloat162 hp = __float22bfloat162_rn(rr);
        unsigned int hu; __builtin_memcpy(&hu, &hp, 4);
        hw[e] = hu;
      }
      hv = make_uint4(hw[0], hw[1], hw[2], hw[3]);
    }
    *reinterpret_cast<uint4*>(dst + s * 8) = hv;
  }
}

__global__ __launch_bounds__(256, 4) void sig_pair_kernel(
    const unsigned short* __restrict__ base, float* __restrict__ acc)
{
  // LDS 33,024 B (4 blocks/CU).
  // GEMM phase: double-buffered staging, buf c&1 @ (c&1)*8192 u16 (A@+0, B@+4096).
  // PDE phase: Qp[129][128] bf16 aliases everything:
  //   even col j: Qp[r][j] = Mp[r][j];  odd col j: Qp[r][j] = Mp[r-1][j]
  //   (Mp[i][j] = M[i-1][j-1] zero-bordered) -> (mE,mO) of one PDE iter = one dword.
  __shared__ unsigned short sm[16512];
  const int tid = threadIdx.x;
  const int bid = blockIdx.x;

  // ---- decode block -> (gram type, a, b, weight) ----
  float w;
  int a, b, srcA, srcB;
  if (bid < 4160) {
    int p = bid;
    srcA = 0;
    if (p >= 2080) { p -= 2080; srcA = 1; }
    srcB = srcA;
    int ia = (int)((sqrtf(8.0f * (float)p + 1.0f) - 1.0f) * 0.5f);
    while ((ia + 1) * (ia + 2) / 2 <= p) ia++;
    while (ia * (ia + 1) / 2 > p) ia--;
    int ib = p - ia * (ia + 1) / 2;
    a = ia; b = ib;
    w = (a == b ? 1.0f : 2.0f) / 4096.0f;
  } else {
    int p = bid - 4160;
    a = p >> 6; b = p & 63;
    srcA = 0; srcB = 1;
    w = -2.0f / 4096.0f;
  }
  const unsigned short* Am = base + srcA * ARR_U16 + a * MAT_U16;
  const unsigned short* Bm = base + srcB * ARR_U16 + b * MAT_U16;

  const int wid = tid >> 6, lane = tid & 63;
  const int row0 = (wid >> 1) * 64, col0 = (wid & 1) * 64;
  const int lrow = lane & 15, quad = lane >> 4;

  // this wave's DMA quarter: waves 0,1 -> A halves; waves 2,3 -> B halves
  const unsigned short* gp = ((wid < 2) ? Am : Bm) + (wid & 1) * 2048 + lane * 8;
  const unsigned int dq = wid * 2048;   // u16 offset inside a staging buf

  floatx4 acc4[4][4];
#pragma unroll
  for (int tr = 0; tr < 4; ++tr)
#pragma unroll
    for (int tc = 0; tc < 4; ++tc) acc4[tr][tc] = (floatx4){0.f, 0.f, 0.f, 0.f};

  // preload chunk 0 into buf 0
#pragma unroll
  for (int s = 0; s < 4; ++s)
    gload_lds16(gp + s * 512, &sm[dq + s * 512]);

  for (int c = 0; c < 4; ++c) {
    __syncthreads();   // drains this wave's DMA (compiler: vmcnt(0) before barrier)
    if (c < 3) {       // prefetch next chunk into the other buffer
      const unsigned short* g = gp + (c + 1) * CHUNK_U16;
      const unsigned int db_ = ((c + 1) & 1) * 8192 + dq;
#pragma unroll
      for (int s = 0; s < 4; ++s)
        gload_lds16(g + s * 512, &sm[db_ + s * 512]);
    }
    const unsigned int bb = (c & 1) * 8192;
    short8 bh[4];
#pragma unroll
    for (int tc = 0; tc < 4; ++tc) {
      int r = col0 + tc * 16 + lrow;
      int off = r * 32 + ((quad ^ (r & 3)) * 8);
      bh[tc] = *reinterpret_cast<const short8*>(&sm[bb + 4096 + off]);
    }
#pragma unroll
    for (int tr = 0; tr < 4; ++tr) {
      int r = row0 + tr * 16 + lrow;
      int off = r * 32 + ((quad ^ (r & 3)) * 8);
      short8 ah = *reinterpret_cast<const short8*>(&sm[bb + off]);
#pragma unroll
      for (int tc = 0; tc < 4; ++tc)
        acc4[tr][tc] = __builtin_amdgcn_mfma_f32_16x16x32_bf16(ah, bh[tc], acc4[tr][tc], 0, 0, 0);
    }
  }
  __syncthreads();   // all staging reads done; alias Qp over the buffer

  // ---- write Qp (bf16): even col j at row i+1, odd col j at row i+2 ----
  {
    unsigned int* qd = reinterpret_cast<unsigned int*>(sm);
    if (tid < 64) {
      qd[tid] = 0;                         // row 0 (all cols)
      sm[128 + 2 * tid + 1] = 0;           // row 1, odd cols
      sm[128 * 128 + 2 * tid] = 0;         // row 128, even cols (NaN safety)
    }
    if (tid < 129) sm[tid * 128] = 0;      // col 0, all rows
  }
#pragma unroll
  for (int tr = 0; tr < 4; ++tr) {
#pragma unroll
    for (int tc = 0; tc < 4; ++tc) {
      int jm = col0 + tc * 16 + lrow;      // M col
#pragma unroll
      for (int e = 0; e < 4; ++e) {
        int im = row0 + tr * 16 + quad * 4 + e;   // M row
        if (im < MM && jm < MM) {
          int j = jm + 1;
          int r = im + 1 + (j & 1);
          sm[r * 128 + j] = f2bf_rne(acc4[tr][tc][e]);
        }
      }
    }
  }
  __syncthreads();

  // ---- Phase 2: 2-col-per-lane PDE, DPP cross-lane, on wave (bid & 3) ----
  // vE = (curE + npE*(m-1)) + ncE   (reassociated: lane-crossing value enters last)
  // lane 0: ncE=0 (DPP bound_ctrl), col-0 border pm=-1, npE init 0 -> stays 1.0.
  if (wid == (bid & 3)) {
    const int l = lane;
    const int l2 = l * 2;
    const unsigned int* q = reinterpret_cast<const unsigned int*>(sm);
    float curE = 1.f, curO = 1.f;
    float npE = (l == 0) ? 0.f : 1.f, npO = 1.f;
    float pmE[4], pmO[4];
    // preload group 0 (d1 = 1..4)
#pragma unroll
    for (int e = 0; e < 4; ++e) {
      int r = 1 + e - l2; r = r < 0 ? 0 : (r > 128 ? 128 : r);
      unsigned int u = q[r * 64 + l];
      pmE[e] = __uint_as_float(u << 16) - 1.0f;
      pmO[e] = __uint_as_float(u & 0xFFFF0000u) - 1.0f;
    }
    for (int g = 0; g < 63; ++g) {         // groups cover d1 = 1..252
      float cmE[4], cmO[4];
#pragma unroll
      for (int e = 0; e < 4; ++e) { cmE[e] = pmE[e]; cmO[e] = pmO[e]; }
      if (g < 62) {
        const int db = 5 + 4 * g;
#pragma unroll
        for (int e = 0; e < 4; ++e) {
          int r = db + e - l2; r = r < 0 ? 0 : (r > 128 ? 128 : r);
          unsigned int u = q[r * 64 + l];
          pmE[e] = __uint_as_float(u << 16) - 1.0f;
          pmO[e] = __uint_as_float(u & 0xFFFF0000u) - 1.0f;
        }
      }
#pragma unroll
      for (int e = 0; e < 4; ++e) {
        float ncE = wave_shr1(curO);
        float ncO = curE;
        float vE = (curE + npE * cmE[e]) + ncE;
        float vO = (curO + npO * cmO[e]) + ncO;
        npE = ncE; npO = ncO;
        curE = vE; curO = vO;
      }
    }
    // tail: d1 = 253, 254
    for (int d1 = 253; d1 <= 254; ++d1) {
      int r = d1 - l2; r = r < 0 ? 0 : (r > 128 ? 128 : r);
      unsigned int u = q[r * 64 + l];
      float mE1 = __uint_as_float(u << 16) - 1.0f;
      float mO1 = __uint_as_float(u & 0xFFFF0000u) - 1.0f;
      float ncE = wave_shr1(curO);
      float ncO = curE;
      float vE = (curE + npE * mE1) + ncE;
      float vO = (curO + npO * mO1) + ncO;
      npE = ncE; npO = ncO;
      curE = vE; curO = vO;
    }
    if (l == 63) atomicAdd(acc, w * curO);   // col 127 = odd col of lane 63
  }
}

__global__ void finalize_kernel(const float* __restrict__ acc,
                                unsigned int* __restrict__ out) {
  float v = acc[0];
  __hip_bfloat16 bv = __float2bfloat16(v);
  unsigned short u;
  __builtin_memcpy(&u, &bv, sizeof(u));
  out[0] = ((unsigned int)u << 16) | (unsigned int)u;
}

extern "C" void kernel_launch(void* const* d_in, const int* in_sizes, int n_in,
                              void* d_out, int out_size, void* d_ws, size_t ws_size,
                              hipStream_t stream) {
  const float* X = (const float*)d_in[0];
  const float* Y = (const float*)d_in[1];
  float* acc = (float*)d_ws;                                     // 4 B @ 0
  unsigned short* base = (unsigned short*)((char*)d_ws + 1024);  // 4 MB arrays

  prep_kernel<<<512, 256, 0, stream>>>(X, Y, base, acc);
  sig_pair_kernel<<<8256, 256, 0, stream>>>(base, acc);
  finalize_kernel<<<1, 1, 0, stream>>>(acc, (unsigned int*)d_out);
}

// Round 11
// 201.605 us; speedup vs baseline: 3.3710x; 1.0153x over previous
//
#include <hip/hip_runtime.h>
#include <hip/hip_bf16.h>

#define MM 127
#define CHUNK_U16 4096        // per (matrix, k-chunk): 512 slots * 8 u16 = 8 KB
#define MAT_U16   16384       // 4 chunks per matrix = 32 KB
#define ARR_U16   1048576     // 64 matrices = 2 MB per array (X, Y)
#define QS_STRIDE 136         // per-lane stream stride (dwords); 136%32=8 -> uniform banks
#define QS_DWORDS (64 * QS_STRIDE)   // 8704 dwords = 34,816 B

typedef __attribute__((ext_vector_type(8))) short short8;
typedef __attribute__((ext_vector_type(4))) float floatx4;

__device__ __forceinline__ unsigned short f2bf_rne(float x) {
  unsigned int u = __float_as_uint(x);
  u += 0x7FFFu + ((u >> 16) & 1u);
  return (unsigned short)(u >> 16);
}

__device__ __forceinline__ void gload_lds16(const void* g, void* l) {
  __builtin_amdgcn_global_load_lds(
      (const __attribute__((address_space(1))) unsigned int*)g,
      (__attribute__((address_space(3))) unsigned int*)l, 16, 0, 0);
}

// wave_shr:1 via DPP: lane l gets lane l-1's value; lane 0 gets 0 (bound_ctrl)
__device__ __forceinline__ float wave_shr1(float x) {
  return __int_as_float(__builtin_amdgcn_update_dpp(
      0, __float_as_int(x), 0x138, 0xf, 0xf, true));
}

// ---- prep: increments -> RNE bf16, stored as the LDS frag image (R9-verified) ----
__global__ __launch_bounds__(256) void prep_kernel(
    const float* __restrict__ X, const float* __restrict__ Y,
    unsigned short* __restrict__ base, float* __restrict__ acc)
{
  if (blockIdx.x == 0 && threadIdx.x == 0) acc[0] = 0.f;
  const int bid = blockIdx.x;
  const int c = bid & 3;
  const int m = (bid >> 2) & 63;
  const int isY = bid >> 8;
  const float* src = (isY ? Y : X) + m * 128 * 128;
  unsigned short* dst = base + isY * ARR_U16 + m * MAT_U16 + c * CHUNK_U16;

  for (int s = threadIdx.x; s < 512; s += 256) {
    const int r = s >> 2;
    const int g = (s & 3) ^ (r & 3);
    uint4 hv = make_uint4(0, 0, 0, 0);
    if (r < MM) {
      const float* p = src + r * 128 + c * 32 + g * 8;
      float4 u0 = *reinterpret_cast<const float4*>(p);
      float4 u1 = *reinterpret_cast<const float4*>(p + 4);
      float4 v0 = *reinterpret_cast<const float4*>(p + 128);
      float4 v1 = *reinterpret_cast<const float4*>(p + 132);
      float d[8] = {v0.x - u0.x, v0.y - u0.y, v0.z - u0.z, v0.w - u0.w,
                    v1.x - u1.x, v1.y - u1.y, v1.z - u1.z, v1.w - u1.w};
      unsigned int hw[4];
#pragma unroll
      for (int e = 0; e < 4; ++e) {
        float2 rr; rr.x = d[2 * e]; rr.y = d[2 * e + 1];
        __hip_bfloat162 hp = __float22bfloat162_rn(rr);
        unsigned int hu; __builtin_memcpy(&hu, &hp, 4);
        hw[e] = hu;
      }
      hv = make_uint4(hw[0], hw[1], hw[2], hw[3]);
    }
    *reinterpret_cast<uint4*>(dst + s * 8) = hv;
  }
}

__global__ __launch_bounds__(256, 4) void sig_pair_kernel(
    const unsigned short* __restrict__ base, float* __restrict__ acc)
{
  // LDS 34,816 B (4 blocks/CU).
  // GEMM phase: double-buffered staging, buf c&1 @ (c&1)*8192 u16 (A@+0, B@+4096).
  // PDE phase: lane-skewed stream qS[64][136] dwords aliases everything:
  //   qS[l][phys] = packed bf16 (mE low, mO high) consumed by lane l at iter t,
  //   phys = t - 4*(l>>1) - 4*(l&1) + 4.  Unwritten slots = 0 -> m-1 = -1 border.
  //   phys 132..135 = dedicated zero pad for pre-band clamped reads.
  __shared__ unsigned int smw[QS_DWORDS];
  unsigned short* const sm = reinterpret_cast<unsigned short*>(smw);
  const int tid = threadIdx.x;
  const int bid = blockIdx.x;

  // ---- decode block -> (gram type, a, b, weight) ----
  float w;
  int a, b, srcA, srcB;
  if (bid < 4160) {
    int p = bid;
    srcA = 0;
    if (p >= 2080) { p -= 2080; srcA = 1; }
    srcB = srcA;
    int ia = (int)((sqrtf(8.0f * (float)p + 1.0f) - 1.0f) * 0.5f);
    while ((ia + 1) * (ia + 2) / 2 <= p) ia++;
    while (ia * (ia + 1) / 2 > p) ia--;
    int ib = p - ia * (ia + 1) / 2;
    a = ia; b = ib;
    w = (a == b ? 1.0f : 2.0f) / 4096.0f;
  } else {
    int p = bid - 4160;
    a = p >> 6; b = p & 63;
    srcA = 0; srcB = 1;
    w = -2.0f / 4096.0f;
  }
  const unsigned short* Am = base + srcA * ARR_U16 + a * MAT_U16;
  const unsigned short* Bm = base + srcB * ARR_U16 + b * MAT_U16;

  const int wid = tid >> 6, lane = tid & 63;
  const int row0 = (wid >> 1) * 64, col0 = (wid & 1) * 64;
  const int lrow = lane & 15, quad = lane >> 4;

  // this wave's DMA quarter: waves 0,1 -> A halves; waves 2,3 -> B halves
  const unsigned short* gp = ((wid < 2) ? Am : Bm) + (wid & 1) * 2048 + lane * 8;
  const unsigned int dq = wid * 2048;   // u16 offset inside a staging buf

  floatx4 acc4[4][4];
#pragma unroll
  for (int tr = 0; tr < 4; ++tr)
#pragma unroll
    for (int tc = 0; tc < 4; ++tc) acc4[tr][tc] = (floatx4){0.f, 0.f, 0.f, 0.f};

  // preload chunk 0 into buf 0
#pragma unroll
  for (int s = 0; s < 4; ++s)
    gload_lds16(gp + s * 512, &sm[dq + s * 512]);

  for (int c = 0; c < 4; ++c) {
    __syncthreads();   // drains DMA (compiler: vmcnt(0) before barrier)
    if (c < 3) {       // prefetch next chunk into the other buffer
      const unsigned short* g = gp + (c + 1) * CHUNK_U16;
      const unsigned int db_ = ((c + 1) & 1) * 8192 + dq;
#pragma unroll
      for (int s = 0; s < 4; ++s)
        gload_lds16(g + s * 512, &sm[db_ + s * 512]);
    }
    const unsigned int bb = (c & 1) * 8192;
    short8 bh[4];
#pragma unroll
    for (int tc = 0; tc < 4; ++tc) {
      int r = col0 + tc * 16 + lrow;
      int off = r * 32 + ((quad ^ (r & 3)) * 8);
      bh[tc] = *reinterpret_cast<const short8*>(&sm[bb + 4096 + off]);
    }
#pragma unroll
    for (int tr = 0; tr < 4; ++tr) {
      int r = row0 + tr * 16 + lrow;
      int off = r * 32 + ((quad ^ (r & 3)) * 8);
      short8 ah = *reinterpret_cast<const short8*>(&sm[bb + off]);
#pragma unroll
      for (int tc = 0; tc < 4; ++tc)
        acc4[tr][tc] = __builtin_amdgcn_mfma_f32_16x16x32_bf16(ah, bh[tc], acc4[tr][tc], 0, 0, 0);
    }
  }
  __syncthreads();   // all staging reads done; alias qS over the buffer

  // ---- zero-fill the stream image (zeros = m-1 == -1 borders) ----
  for (int i = tid; i < QS_DWORDS; i += 256) smw[i] = 0u;
  __syncthreads();

  // ---- epilogue: write M (bf16) directly into consumer (lane, slot) ----
  // odd jm -> E (low u16) of lane (jm+1)/2; even jm -> O (high u16) of lane jm/2.
  // phys = im + jm + 5 - 4*(lt>>1) - 4*(lt&1)
#pragma unroll
  for (int tr = 0; tr < 4; ++tr) {
#pragma unroll
    for (int tc = 0; tc < 4; ++tc) {
      int jm = col0 + tc * 16 + lrow;
#pragma unroll
      for (int e = 0; e < 4; ++e) {
        int im = row0 + tr * 16 + quad * 4 + e;
        if (im < MM && jm < MM) {
          int lt = (jm + 1) >> 1;
          int phys = im + jm + 5 - 4 * (lt >> 1) - 4 * (lt & 1);
          int half = (jm & 1) ? 0 : 1;
          sm[(lt * QS_STRIDE + phys) * 2 + half] = f2bf_rne(acc4[tr][tc][e]);
        }
      }
    }
  }
  __syncthreads();

  // ---- Phase 2: streamed PDE, DPP cross-lane, on wave (bid & 3) ----
  // vE = (curE + npE*(m-1)) + ncE ; lane0 E self-sustains at 1 (npE=0, DPP bc).
  if (wid == (bid & 3)) {
    const int l = lane;
    const int shift = 4 * (l >> 1) + 4 * (l & 1) - 4;
    const unsigned int lbase = l * QS_STRIDE;

    auto loadg = [&](int g) -> uint4 {
      int pb = 4 * g - shift;
      pb = pb < 0 ? 132 : (pb > 128 ? 128 : pb);   // pre-band -> zero pad; post-band contained
      return *reinterpret_cast<const uint4*>(&smw[lbase + pb]);
    };

    float curE = 1.f, curO = 1.f;
    float npE = (l == 0) ? 0.f : 1.f, npO = 1.f;
    uint4 P0 = loadg(0), P1 = loadg(1);

    for (int g = 0; g < 63; ++g) {       // groups cover t = 0..251
      const uint4 cur = P0;
      P0 = P1;
      if (g < 62) P1 = loadg(g + 2);
      unsigned int uu[4] = {cur.x, cur.y, cur.z, cur.w};
#pragma unroll
      for (int e = 0; e < 4; ++e) {
        unsigned int u = uu[e];
        float mE = __uint_as_float(u << 16) - 1.0f;
        float mO = __uint_as_float(u & 0xFFFF0000u) - 1.0f;
        float ncE = wave_shr1(curO);
        float ncO = curE;
        float vE = (curE + npE * mE) + ncE;
        float vO = (curO + npO * mO) + ncO;
        npE = ncE; npO = ncO;
        curE = vE; curO = vO;
      }
    }
    // tail: t = 252, 253 from group 63 (already in P0)
    {
      unsigned int uu[2] = {P0.x, P0.y};
#pragma unroll
      for (int e = 0; e < 2; ++e) {
        unsigned int u = uu[e];
        float mE = __uint_as_float(u << 16) - 1.0f;
        float mO = __uint_as_float(u & 0xFFFF0000u) - 1.0f;
        float ncE = wave_shr1(curO);
        float ncO = curE;
        float vE = (curE + npE * mE) + ncE;
        float vO = (curO + npO * mO) + ncO;
        npE = ncE; npO = ncO;
        curE = vE; curO = vO;
      }
    }
    if (l == 63) atomicAdd(acc, w * curO);   // col 127 = odd col of lane 63
  }
}

__global__ void finalize_kernel(const float* __restrict__ acc,
                                unsigned int* __restrict__ out) {
  float v = acc[0];
  __hip_bfloat16 bv = __float2bfloat16(v);
  unsigned short u;
  __builtin_memcpy(&u, &bv, sizeof(u));
  out[0] = ((unsigned int)u << 16) | (unsigned int)u;
}

extern "C" void kernel_launch(void* const* d_in, const int* in_sizes, int n_in,
                              void* d_out, int out_size, void* d_ws, size_t ws_size,
                              hipStream_t stream) {
  const float* X = (const float*)d_in[0];
  const float* Y = (const float*)d_in[1];
  float* acc = (float*)d_ws;                                     // 4 B @ 0
  unsigned short* base = (unsigned short*)((char*)d_ws + 1024);  // 4 MB arrays

  prep_kernel<<<512, 256, 0, stream>>>(X, Y, base, acc);
  sig_pair_kernel<<<8256, 256, 0, stream>>>(base, acc);
  finalize_kernel<<<1, 1, 0, stream>>>(acc, (unsigned int*)d_out);
}